// Round 1
// baseline (778.309 us; speedup 1.0000x reference)
//
#include <hip/hip_runtime.h>
#include <hip/hip_bf16.h>
#include <math.h>

// Fused MLP projector: emb[16384,1024] @ W1[1024,4096] + b1 -> LN -> GELU(erf)
// -> @ W2[4096,1024] -> out fp32.
// Strategy: bf16 MFMA GEMMs (threshold 4.19e-2 = 8*bf16eps*max|ref| tolerates it).
// ws layout (bytes):
//   [0, 128M)            h bf16 [16384][4096]
//   [128M, 160M)         emb bf16 [16384][1024]
//   [160M, 168M)         W1^T bf16 [4096][1024]
//   [168M, 176M)         W2^T bf16 [1024][4096]

typedef unsigned short ushort_t;
typedef __bf16 bf16x8 __attribute__((ext_vector_type(8)));
typedef float f32x4 __attribute__((ext_vector_type(4)));

__device__ __forceinline__ ushort_t f2bf(float f) {
  unsigned u = __builtin_bit_cast(unsigned, f);
  u += 0x7FFFu + ((u >> 16) & 1u);   // round-to-nearest-even
  return (ushort_t)(u >> 16);
}

__device__ __forceinline__ void gload_lds16(const void* g, void* l) {
  // async global->LDS, 16B per lane; LDS dest = wave-uniform base + lane*16
  __builtin_amdgcn_global_load_lds(
      (const __attribute__((address_space(1))) void*)g,
      (__attribute__((address_space(3))) void*)l, 16, 0, 0);
}

// ---------------- cast fp32 -> bf16 (elementwise) ----------------
__global__ void __launch_bounds__(256) cast_kernel(const float* __restrict__ in,
                                                   ushort_t* __restrict__ out,
                                                   long n) {
  long i = ((long)blockIdx.x * 256 + threadIdx.x) * 4;
  const long stride = (long)gridDim.x * 256 * 4;
  for (; i < n; i += stride) {
    float4 v = *(const float4*)(in + i);
    ushort4 o;
    o.x = f2bf(v.x); o.y = f2bf(v.y); o.z = f2bf(v.z); o.w = f2bf(v.w);
    *(ushort4*)(out + i) = o;
  }
}

// ---------------- transpose + cast: in[R][C] f32 -> out[C][R] bf16 ----------------
__global__ void __launch_bounds__(256) transpose_cast(const float* __restrict__ in,
                                                      ushort_t* __restrict__ out,
                                                      int R, int C) {
  __shared__ float tile[32][33];  // +1 pad: conflict-free transposed read
  const int bx = blockIdx.x * 32;  // C index
  const int by = blockIdx.y * 32;  // R index
  const int tx = threadIdx.x;      // 0..31
  const int ty = threadIdx.y;      // 0..7
#pragma unroll
  for (int i = 0; i < 32; i += 8)
    tile[ty + i][tx] = in[(long)(by + ty + i) * C + (bx + tx)];
  __syncthreads();
#pragma unroll
  for (int i = 0; i < 32; i += 8)
    out[(long)(bx + ty + i) * R + (by + tx)] = f2bf(tile[tx][ty + i]);
}

// ---------------- bf16 GEMM, C = A @ Bt^T (+bias), m97 structure ----------------
// A [M][K] bf16 row-major, Bt [N][K] bf16 row-major. 128x128 tile, BK=32,
// 4 waves in 2x2, each wave 64x64 via 4x4 frags of 16x16x32 MFMA.
// EPI=0: bf16 store with +bias[col]; EPI=1: fp32 store, no bias.
template <int EPI>
__global__ void __launch_bounds__(256) gemm_bt(const ushort_t* __restrict__ A,
                                               const ushort_t* __restrict__ Bt,
                                               const float* __restrict__ bias,
                                               void* __restrict__ Cout,
                                               int M, int N, int K) {
  __shared__ ushort_t As[128 * 32];
  __shared__ ushort_t Bs[128 * 32];
  const int tid = threadIdx.x;
  const int lane = tid & 63;
  const int wid = tid >> 6;
  const int wr = wid >> 1;       // wave row (0..1)
  const int wc = wid & 1;        // wave col (0..1)
  const long bm = (long)blockIdx.y * 128;
  const long bn = (long)blockIdx.x * 128;

  f32x4 acc[4][4] = {};

  // staging: linear idx = t*256+tid; row = idx>>2 (32 bf16/row = 4 lanes x 16B)
  const ushort_t* Ag = A + (bm + (tid >> 2)) * (long)K + (tid & 3) * 8;
  const ushort_t* Bg = Bt + (bn + (tid >> 2)) * (long)K + (tid & 3) * 8;
  ushort_t* AsW = &As[tid * 8];
  ushort_t* BsW = &Bs[tid * 8];

  // fragment read offsets (ushort units): [row][k] with row-stride 32
  const int aOff = (wr * 64 + (lane & 15)) * 32 + (lane >> 4) * 8;
  const int bOff = (wc * 64 + (lane & 15)) * 32 + (lane >> 4) * 8;

  for (int k0 = 0; k0 < K; k0 += 32) {
    gload_lds16(Ag + k0, AsW);
    gload_lds16(Ag + (long)64 * K + k0, AsW + 2048);
    gload_lds16(Bg + k0, BsW);
    gload_lds16(Bg + (long)64 * K + k0, BsW + 2048);
    __syncthreads();  // compiler emits vmcnt(0) drain before barrier

    bf16x8 af[4], bfv[4];
#pragma unroll
    for (int i = 0; i < 4; ++i) af[i] = *(const bf16x8*)&As[aOff + i * 16 * 32];
#pragma unroll
    for (int j = 0; j < 4; ++j) bfv[j] = *(const bf16x8*)&Bs[bOff + j * 16 * 32];
#pragma unroll
    for (int i = 0; i < 4; ++i)
#pragma unroll
      for (int j = 0; j < 4; ++j)
        acc[i][j] = __builtin_amdgcn_mfma_f32_16x16x32_bf16(af[i], bfv[j],
                                                            acc[i][j], 0, 0, 0);
    __syncthreads();
  }

  // C/D layout (verified m89/m91): col = lane&15, row = (lane>>4)*4 + reg
  const long r0 = bm + wr * 64 + (lane >> 4) * 4;
  const long c0 = bn + wc * 64 + (lane & 15);
  if (EPI == 0) {
    ushort_t* C = (ushort_t*)Cout;
#pragma unroll
    for (int j = 0; j < 4; ++j) {
      const long col = c0 + j * 16;
      const float bv = bias[col];
#pragma unroll
      for (int i = 0; i < 4; ++i)
#pragma unroll
        for (int r = 0; r < 4; ++r)
          C[(r0 + i * 16 + r) * N + col] = f2bf(acc[i][j][r] + bv);
    }
  } else {
    float* C = (float*)Cout;
#pragma unroll
    for (int j = 0; j < 4; ++j) {
      const long col = c0 + j * 16;
#pragma unroll
      for (int i = 0; i < 4; ++i)
#pragma unroll
        for (int r = 0; r < 4; ++r)
          C[(r0 + i * 16 + r) * N + col] = acc[i][j][r];
    }
  }
}

// ---------------- LayerNorm + exact GELU, in-place on bf16 h ----------------
// one block per row of 4096; 256 threads x 16 elems kept in registers
__global__ void __launch_bounds__(256) ln_gelu(ushort_t* __restrict__ h,
                                               const float* __restrict__ gamma,
                                               const float* __restrict__ beta) {
  const int D = 4096;
  ushort_t* p = h + (long)blockIdx.x * D + threadIdx.x * 16;
  uint4 u0 = *(const uint4*)p;
  uint4 u1 = *(const uint4*)(p + 8);
  unsigned w[8] = {u0.x, u0.y, u0.z, u0.w, u1.x, u1.y, u1.z, u1.w};
  float x[16];
#pragma unroll
  for (int k = 0; k < 8; ++k) {
    x[2 * k]     = __builtin_bit_cast(float, w[k] << 16);
    x[2 * k + 1] = __builtin_bit_cast(float, w[k] & 0xFFFF0000u);
  }
  float s = 0.f, q = 0.f;
#pragma unroll
  for (int k = 0; k < 16; ++k) { s += x[k]; q += x[k] * x[k]; }
#pragma unroll
  for (int m = 1; m < 64; m <<= 1) {
    s += __shfl_xor(s, m, 64);
    q += __shfl_xor(q, m, 64);
  }
  __shared__ float rs[4], rq[4];
  const int wid = threadIdx.x >> 6;
  if ((threadIdx.x & 63) == 0) { rs[wid] = s; rq[wid] = q; }
  __syncthreads();
  s = rs[0] + rs[1] + rs[2] + rs[3];
  q = rq[0] + rq[1] + rq[2] + rq[3];
  const float mu = s * (1.f / 4096.f);
  const float var = q * (1.f / 4096.f) - mu * mu;
  const float rstd = rsqrtf(var + 1e-5f);
  const int cb = threadIdx.x * 16;
  unsigned o[8];
#pragma unroll
  for (int k = 0; k < 16; ++k) {
    float y = (x[k] - mu) * rstd * gamma[cb + k] + beta[cb + k];
    float g = 0.5f * y * (1.f + erff(y * 0.70710678118654752f));
    ushort_t b = f2bf(g);
    if (k & 1) o[k >> 1] |= ((unsigned)b) << 16; else o[k >> 1] = (unsigned)b;
  }
  uint4 v0, v1;
  v0.x = o[0]; v0.y = o[1]; v0.z = o[2]; v0.w = o[3];
  v1.x = o[4]; v1.y = o[5]; v1.z = o[6]; v1.w = o[7];
  *(uint4*)p = v0;
  *(uint4*)(p + 8) = v1;
}

extern "C" void kernel_launch(void* const* d_in, const int* in_sizes, int n_in,
                              void* d_out, int out_size, void* d_ws, size_t ws_size,
                              hipStream_t stream) {
  const float* emb   = (const float*)d_in[0];
  const float* W1    = (const float*)d_in[1];
  const float* b1    = (const float*)d_in[2];
  const float* gamma = (const float*)d_in[3];
  const float* beta  = (const float*)d_in[4];
  const float* W2    = (const float*)d_in[5];
  float* out = (float*)d_out;

  const int B = 16384, DIN = 1024, DH = 4096, DOUT = 1024;
  char* ws = (char*)d_ws;
  ushort_t* h    = (ushort_t*)(ws);                 // 134217728 B
  ushort_t* embB = (ushort_t*)(ws + 134217728);     //  33554432 B
  ushort_t* w1t  = (ushort_t*)(ws + 167772160);     //   8388608 B
  ushort_t* w2t  = (ushort_t*)(ws + 176160768);     //   8388608 B

  cast_kernel<<<4096, 256, 0, stream>>>(emb, embB, (long)B * DIN);
  transpose_cast<<<dim3(DH / 32, DIN / 32), dim3(32, 8), 0, stream>>>(W1, w1t, DIN, DH);
  transpose_cast<<<dim3(DOUT / 32, DH / 32), dim3(32, 8), 0, stream>>>(W2, w2t, DH, DOUT);
  gemm_bt<0><<<dim3(DH / 128, B / 128), 256, 0, stream>>>(embB, w1t, b1, h, B, DH, DIN);
  ln_gelu<<<B, 256, 0, stream>>>(h, gamma, beta);
  gemm_bt<1><<<dim3(DOUT / 128, B / 128), 256, 0, stream>>>(h, w2t, nullptr, out, B, DOUT, DH);
}

// Round 2
// 583.582 us; speedup vs baseline: 1.3337x; 1.3337x over previous
//
#include <hip/hip_runtime.h>
#include <hip/hip_bf16.h>
#include <math.h>

// Fused MLP projector: emb[16384,1024] @ W1[1024,4096] + b1 -> LN -> GELU
// -> @ W2[4096,1024] -> out fp32.
// bf16 MFMA GEMMs (m97 structure) + fast tanh-GELU (erf path was 257us of 778).
// ws layout (bytes):
//   [0, 128M)            h bf16 [16384][4096]
//   [128M, 160M)         emb bf16 [16384][1024]
//   [160M, 168M)         W1^T bf16 [4096][1024]
//   [168M, 176M)         W2^T bf16 [1024][4096]

typedef unsigned short ushort_t;
typedef __bf16 bf16x8 __attribute__((ext_vector_type(8)));
typedef float f32x4 __attribute__((ext_vector_type(4)));

__device__ __forceinline__ ushort_t f2bf(float f) {
  unsigned u = __builtin_bit_cast(unsigned, f);
  u += 0x7FFFu + ((u >> 16) & 1u);   // round-to-nearest-even
  return (ushort_t)(u >> 16);
}

__device__ __forceinline__ void gload_lds16(const void* g, void* l) {
  // async global->LDS, 16B per lane; LDS dest = wave-uniform base + lane*16
  __builtin_amdgcn_global_load_lds(
      (const __attribute__((address_space(1))) void*)g,
      (__attribute__((address_space(3))) void*)l, 16, 0, 0);
}

// ---------------- cast fp32 -> bf16 (elementwise) ----------------
__global__ void __launch_bounds__(256) cast_kernel(const float* __restrict__ in,
                                                   ushort_t* __restrict__ out,
                                                   long n) {
  long i = ((long)blockIdx.x * 256 + threadIdx.x) * 4;
  const long stride = (long)gridDim.x * 256 * 4;
  for (; i < n; i += stride) {
    float4 v = *(const float4*)(in + i);
    ushort4 o;
    o.x = f2bf(v.x); o.y = f2bf(v.y); o.z = f2bf(v.z); o.w = f2bf(v.w);
    *(ushort4*)(out + i) = o;
  }
}

// ---------------- transpose + cast: in[R][C] f32 -> out[C][R] bf16 ----------------
__global__ void __launch_bounds__(256) transpose_cast(const float* __restrict__ in,
                                                      ushort_t* __restrict__ out,
                                                      int R, int C) {
  __shared__ float tile[32][33];  // +1 pad: conflict-free transposed read
  const int bx = blockIdx.x * 32;  // C index
  const int by = blockIdx.y * 32;  // R index
  const int tx = threadIdx.x;      // 0..31
  const int ty = threadIdx.y;      // 0..7
#pragma unroll
  for (int i = 0; i < 32; i += 8)
    tile[ty + i][tx] = in[(long)(by + ty + i) * C + (bx + tx)];
  __syncthreads();
#pragma unroll
  for (int i = 0; i < 32; i += 8)
    out[(long)(bx + ty + i) * R + (by + tx)] = f2bf(tile[tx][ty + i]);
}

// ---------------- bf16 GEMM, C = A @ Bt^T (+bias), m97 structure ----------------
// A [M][K] bf16 row-major, Bt [N][K] bf16 row-major. 128x128 tile, BK=32,
// 4 waves in 2x2, each wave 64x64 via 4x4 frags of 16x16x32 MFMA.
// Flattened 1D grid with bijective XCD swizzle (T1); nwg % 8 == 0 guaranteed.
// EPI=0: bf16 store with +bias[col]; EPI=1: fp32 store, no bias.
template <int EPI>
__global__ void __launch_bounds__(256) gemm_bt(const ushort_t* __restrict__ A,
                                               const ushort_t* __restrict__ Bt,
                                               const float* __restrict__ bias,
                                               void* __restrict__ Cout,
                                               int N, int K, int nbn) {
  __shared__ ushort_t As[128 * 32];
  __shared__ ushort_t Bs[128 * 32];
  const int tid = threadIdx.x;
  const int lane = tid & 63;
  const int wid = tid >> 6;
  const int wr = wid >> 1;       // wave row (0..1)
  const int wc = wid & 1;        // wave col (0..1)

  // XCD-aware bijective swizzle: XCD x owns contiguous tile chunk
  const int nwg = gridDim.x;
  const int cpx = nwg >> 3;
  const int tile = (blockIdx.x & 7) * cpx + (blockIdx.x >> 3);
  const long bm = (long)(tile / nbn) * 128;
  const long bn = (long)(tile % nbn) * 128;

  f32x4 acc[4][4] = {};

  // staging: row = tid>>2 (32 bf16/row = 4 lanes x 16B)
  const ushort_t* Ag = A + (bm + (tid >> 2)) * (long)K + (tid & 3) * 8;
  const ushort_t* Bg = Bt + (bn + (tid >> 2)) * (long)K + (tid & 3) * 8;
  ushort_t* AsW = &As[tid * 8];
  ushort_t* BsW = &Bs[tid * 8];

  // fragment read offsets (ushort units): [row][k] with row-stride 32
  const int aOff = (wr * 64 + (lane & 15)) * 32 + (lane >> 4) * 8;
  const int bOff = (wc * 64 + (lane & 15)) * 32 + (lane >> 4) * 8;

  for (int k0 = 0; k0 < K; k0 += 32) {
    gload_lds16(Ag + k0, AsW);
    gload_lds16(Ag + (long)64 * K + k0, AsW + 2048);
    gload_lds16(Bg + k0, BsW);
    gload_lds16(Bg + (long)64 * K + k0, BsW + 2048);
    __syncthreads();

    bf16x8 af[4], bfv[4];
#pragma unroll
    for (int i = 0; i < 4; ++i) af[i] = *(const bf16x8*)&As[aOff + i * 16 * 32];
#pragma unroll
    for (int j = 0; j < 4; ++j) bfv[j] = *(const bf16x8*)&Bs[bOff + j * 16 * 32];
#pragma unroll
    for (int i = 0; i < 4; ++i)
#pragma unroll
      for (int j = 0; j < 4; ++j)
        acc[i][j] = __builtin_amdgcn_mfma_f32_16x16x32_bf16(af[i], bfv[j],
                                                            acc[i][j], 0, 0, 0);
    __syncthreads();
  }

  // C/D layout (verified m89/m91): col = lane&15, row = (lane>>4)*4 + reg
  const long r0 = bm + wr * 64 + (lane >> 4) * 4;
  const long c0 = bn + wc * 64 + (lane & 15);
  if (EPI == 0) {
    ushort_t* C = (ushort_t*)Cout;
#pragma unroll
    for (int j = 0; j < 4; ++j) {
      const long col = c0 + j * 16;
      const float bv = bias[col];
#pragma unroll
      for (int i = 0; i < 4; ++i)
#pragma unroll
        for (int r = 0; r < 4; ++r)
          C[(r0 + i * 16 + r) * N + col] = f2bf(acc[i][j][r] + bv);
    }
  } else {
    float* C = (float*)Cout;
#pragma unroll
    for (int j = 0; j < 4; ++j) {
      const long col = c0 + j * 16;
#pragma unroll
      for (int i = 0; i < 4; ++i)
#pragma unroll
        for (int r = 0; r < 4; ++r)
          C[(r0 + i * 16 + r) * N + col] = acc[i][j][r];
    }
  }
}

// ---------------- LayerNorm + fast GELU, in-place on bf16 h ----------------
// one block per row of 4096; 256 threads x 16 elems kept in registers.
// GELU via tanh-form sigmoid: g = y * rcp(1 + exp(-1.5957691*(y+0.044715*y^3)))
// (erf-exact path cost 257us: divergent two-path __ocml_erf_f32 + IEEE divs)
__global__ void __launch_bounds__(256) ln_gelu(ushort_t* __restrict__ h,
                                               const float* __restrict__ gamma,
                                               const float* __restrict__ beta) {
  const int D = 4096;
  ushort_t* p = h + (long)blockIdx.x * D + threadIdx.x * 16;
  uint4 u0 = *(const uint4*)p;
  uint4 u1 = *(const uint4*)(p + 8);
  unsigned w[8] = {u0.x, u0.y, u0.z, u0.w, u1.x, u1.y, u1.z, u1.w};
  float x[16];
#pragma unroll
  for (int k = 0; k < 8; ++k) {
    x[2 * k]     = __builtin_bit_cast(float, w[k] << 16);
    x[2 * k + 1] = __builtin_bit_cast(float, w[k] & 0xFFFF0000u);
  }
  float s = 0.f, q = 0.f;
#pragma unroll
  for (int k = 0; k < 16; ++k) { s += x[k]; q += x[k] * x[k]; }
#pragma unroll
  for (int m = 1; m < 64; m <<= 1) {
    s += __shfl_xor(s, m, 64);
    q += __shfl_xor(q, m, 64);
  }
  __shared__ float rs[4], rq[4];
  const int wid = threadIdx.x >> 6;
  if ((threadIdx.x & 63) == 0) { rs[wid] = s; rq[wid] = q; }
  __syncthreads();
  s = rs[0] + rs[1] + rs[2] + rs[3];
  q = rq[0] + rq[1] + rq[2] + rq[3];
  const float mu = s * (1.f / 4096.f);
  const float var = q * (1.f / 4096.f) - mu * mu;
  const float rstd = rsqrtf(var + 1e-5f);

  const int cb = threadIdx.x * 16;
  float gm[16], bt[16];
#pragma unroll
  for (int k = 0; k < 4; ++k) {
    *(float4*)&gm[k * 4] = *(const float4*)&gamma[cb + k * 4];
    *(float4*)&bt[k * 4] = *(const float4*)&beta[cb + k * 4];
  }
  unsigned o[8];
#pragma unroll
  for (int k = 0; k < 16; ++k) {
    float y = (x[k] - mu) * rstd * gm[k] + bt[k];
    float z = -1.5957691216f * __builtin_fmaf(0.044715f * y, y * y, y);
    float g = y * __builtin_amdgcn_rcpf(1.f + __expf(z));
    ushort_t b = f2bf(g);
    if (k & 1) o[k >> 1] |= ((unsigned)b) << 16; else o[k >> 1] = (unsigned)b;
  }
  uint4 v0, v1;
  v0.x = o[0]; v0.y = o[1]; v0.z = o[2]; v0.w = o[3];
  v1.x = o[4]; v1.y = o[5]; v1.z = o[6]; v1.w = o[7];
  *(uint4*)p = v0;
  *(uint4*)(p + 8) = v1;
}

extern "C" void kernel_launch(void* const* d_in, const int* in_sizes, int n_in,
                              void* d_out, int out_size, void* d_ws, size_t ws_size,
                              hipStream_t stream) {
  const float* emb   = (const float*)d_in[0];
  const float* W1    = (const float*)d_in[1];
  const float* b1    = (const float*)d_in[2];
  const float* gamma = (const float*)d_in[3];
  const float* beta  = (const float*)d_in[4];
  const float* W2    = (const float*)d_in[5];
  float* out = (float*)d_out;

  const int B = 16384, DIN = 1024, DH = 4096, DOUT = 1024;
  char* ws = (char*)d_ws;
  ushort_t* h    = (ushort_t*)(ws);                 // 134217728 B
  ushort_t* embB = (ushort_t*)(ws + 134217728);     //  33554432 B
  ushort_t* w1t  = (ushort_t*)(ws + 167772160);     //   8388608 B
  ushort_t* w2t  = (ushort_t*)(ws + 176160768);     //   8388608 B

  cast_kernel<<<4096, 256, 0, stream>>>(emb, embB, (long)B * DIN);
  transpose_cast<<<dim3(DH / 32, DIN / 32), dim3(32, 8), 0, stream>>>(W1, w1t, DIN, DH);
  transpose_cast<<<dim3(DOUT / 32, DH / 32), dim3(32, 8), 0, stream>>>(W2, w2t, DH, DOUT);
  gemm_bt<0><<<(B / 128) * (DH / 128), 256, 0, stream>>>(embB, w1t, b1, h, DH, DIN, DH / 128);
  ln_gelu<<<B, 256, 0, stream>>>(h, gamma, beta);
  gemm_bt<1><<<(B / 128) * (DOUT / 128), 256, 0, stream>>>(h, w2t, nullptr, out, DOUT, DH, DOUT / 128);
}

// Round 5
// 469.779 us; speedup vs baseline: 1.6568x; 1.2422x over previous
//
#include <hip/hip_runtime.h>
#include <hip/hip_bf16.h>
#include <math.h>

// Fused MLP projector: emb[16384,1024] @ W1[1024,4096] + b1 -> LN -> GELU
// -> @ W2[4096,1024] -> out fp32.
// bf16 MFMA GEMMs: 256x256 8-phase schedule (T2 swizzle + T3/T4 counted vmcnt
// + T5 setprio). Round-4 fix: prologue now drains vmcnt(0) after issuing ALL
// 12 staging loads (compiler may reorder independent global_load_lds within
// the unfenced prologue, which made vmcnt(4) cover the wrong 8 loads -> the
// replay-only race in round 3); post-loop vmcnt(0) retires tail prefetches.
// (Round 5 = identical resubmit: round-4 bench was an infra failure, the
// kernel never executed.)
// ws layout (bytes):
//   [0, 128M)            h bf16 [16384][4096]
//   [128M, 160M)         emb bf16 [16384][1024]
//   [160M, 168M)         W1^T bf16 [4096][1024]
//   [168M, 176M)         W2^T bf16 [1024][4096]

typedef unsigned short ushort_t;
typedef __bf16 bf16x8 __attribute__((ext_vector_type(8)));
typedef float f32x4 __attribute__((ext_vector_type(4)));

__device__ __forceinline__ ushort_t f2bf(float f) {
  unsigned u = __builtin_bit_cast(unsigned, f);
  u += 0x7FFFu + ((u >> 16) & 1u);   // round-to-nearest-even
  return (ushort_t)(u >> 16);
}

__device__ __forceinline__ void gload_lds16(const void* g, void* l) {
  // async global->LDS, 16B/lane; LDS dest = affine base + lane*16
  __builtin_amdgcn_global_load_lds(
      (const __attribute__((address_space(1))) void*)g,
      (__attribute__((address_space(3))) void*)l, 16, 0, 0);
}

// ---------------- cast fp32 -> bf16 ----------------
__global__ void __launch_bounds__(256) cast_kernel(const float* __restrict__ in,
                                                   ushort_t* __restrict__ out,
                                                   long n) {
  long i = ((long)blockIdx.x * 256 + threadIdx.x) * 4;
  const long stride = (long)gridDim.x * 256 * 4;
  for (; i < n; i += stride) {
    float4 v = *(const float4*)(in + i);
    ushort4 o;
    o.x = f2bf(v.x); o.y = f2bf(v.y); o.z = f2bf(v.z); o.w = f2bf(v.w);
    *(ushort4*)(out + i) = o;
  }
}

// ---------------- transpose + cast: in[R][C] f32 -> out[C][R] bf16 ----------------
__global__ void __launch_bounds__(256) transpose_cast(const float* __restrict__ in,
                                                      ushort_t* __restrict__ out,
                                                      int R, int C) {
  __shared__ float tile[32][33];
  const int bx = blockIdx.x * 32;
  const int by = blockIdx.y * 32;
  const int tx = threadIdx.x;
  const int ty = threadIdx.y;
#pragma unroll
  for (int i = 0; i < 32; i += 8)
    tile[ty + i][tx] = in[(long)(by + ty + i) * C + (bx + tx)];
  __syncthreads();
#pragma unroll
  for (int i = 0; i < 32; i += 8)
    out[(long)(bx + ty + i) * R + (by + tx)] = f2bf(tile[tx][ty + i]);
}

// ================ 256x256 8-phase bf16 GEMM, C = A @ Bt^T ================
// A [M][K], Bt [N][K] bf16 row-major. 512 thr = 8 waves (2M x 4N); per-wave
// out 128x64 = acc[8][4] f32x4. BK=64; 2 K-tiles/iter; LDS 128 KiB:
//   A0/A1/B0/B1 tile bufs, each [256 rows][8 slots of 16B], slot = kb^(row&7)
// (T2 swizzle; staged via linear-dest gload_lds + inverse-swizzled source).

__device__ __forceinline__ void stage_half(ushort_t* dst, const ushort_t* gRow,
                                           long K, int tid, int rS, int kbS) {
  gload_lds16(gRow + (long)rS * K + kbS * 8, dst + (size_t)tid * 8);
  gload_lds16(gRow + (long)(rS + 64) * K + kbS * 8, dst + (size_t)(512 + tid) * 8);
}

template <int Q, bool LOADB, bool VMW>
__device__ __forceinline__ void phase(f32x4 (&acc)[8][4], bf16x8 (&b)[4][2],
                                      const ushort_t* aT, const ushort_t* bT,
                                      int rowA, int rowB, int kHi,
                                      const ushort_t* pfSrc, ushort_t* pfDst,
                                      long K, int tid, int rS, int kbS) {
  if (LOADB) {
#pragma unroll
    for (int j = 0; j < 4; ++j) {
      const int row = rowB + j * 16;
      const int sw = row & 7;
#pragma unroll
      for (int s = 0; s < 2; ++s)
        b[j][s] = *(const bf16x8*)(bT + row * 64 + ((s * 4 + kHi) ^ sw) * 8);
    }
  }
  bf16x8 a[2][2];
#pragma unroll
  for (int di = 0; di < 2; ++di) {
    const int row = rowA + (2 * Q + di) * 16;
    const int sw = row & 7;
#pragma unroll
    for (int s = 0; s < 2; ++s)
      a[di][s] = *(const bf16x8*)(aT + row * 64 + ((s * 4 + kHi) ^ sw) * 8);
  }
  stage_half(pfDst, pfSrc, K, tid, rS, kbS);   // 1 half-tile prefetch (2 loads)
  asm volatile("" ::: "memory");
  __builtin_amdgcn_s_barrier();
  asm volatile("s_waitcnt lgkmcnt(0)" ::: "memory");
  __builtin_amdgcn_s_setprio(1);
#pragma unroll
  for (int di = 0; di < 2; ++di)
#pragma unroll
    for (int s = 0; s < 2; ++s)
#pragma unroll
      for (int j = 0; j < 4; ++j)
        acc[2 * Q + di][j] = __builtin_amdgcn_mfma_f32_16x16x32_bf16(
            a[di][s], b[j][s], acc[2 * Q + di][j], 0, 0, 0);
  __builtin_amdgcn_s_setprio(0);
  if (VMW) asm volatile("s_waitcnt vmcnt(4)" ::: "memory");  // counted, never 0
  asm volatile("" ::: "memory");
  __builtin_amdgcn_s_barrier();
  asm volatile("" ::: "memory");
}

template <int EPI>
__global__ void __launch_bounds__(512, 2) gemm256(const ushort_t* __restrict__ A,
                                                  const ushort_t* __restrict__ Bt,
                                                  const float* __restrict__ bias,
                                                  void* __restrict__ Cout,
                                                  int N, int K, int nbn) {
  __shared__ __align__(16) ushort_t lds[65536];  // 128 KiB
  const int tid = threadIdx.x;
  const int lane = tid & 63;
  const int wid = tid >> 6;
  const int wr = wid >> 2;       // 0..1
  const int wc = wid & 3;        // 0..3

  // XCD-aware bijective swizzle (nwg % 8 == 0 by construction)
  const int nwg = gridDim.x;
  const int cpx = nwg >> 3;
  const int tile = (blockIdx.x & 7) * cpx + (blockIdx.x >> 3);
  const long bm = (long)(tile / nbn) * 256;
  const long bn = (long)(tile % nbn) * 256;

  ushort_t* A0 = lds;
  ushort_t* A1 = lds + 16384;
  ushort_t* B0 = lds + 32768;
  ushort_t* B1 = lds + 49152;

  const ushort_t* Arow = A + bm * (long)K;
  const ushort_t* Brow = Bt + bn * (long)K;

  const int rS = tid >> 3;                 // staging row (0..63) in half
  const int kbS = (tid & 7) ^ (rS & 7);    // inverse-swizzled source k-block
  const int rowA = wr * 128 + (lane & 15);
  const int rowB = wc * 64 + (lane & 15);
  const int kHi = lane >> 4;

  f32x4 acc[8][4] = {};
  bf16x8 bfr[4][2];

  // prologue: T0 (A+B) -> buf0, B(T1) -> buf1; FULL vmcnt(0) drain so the
  // first-wait correctness does not depend on compiler issue order of the 12
  // independent loads (the round-3 replay race). A(T1) is staged in ph1-2.
  stage_half(A0, Arow, K, tid, rS, kbS);
  stage_half(A0 + 8192, Arow + 128L * K, K, tid, rS, kbS);
  stage_half(B0, Brow, K, tid, rS, kbS);
  stage_half(B0 + 8192, Brow + 128L * K, K, tid, rS, kbS);
  stage_half(B1, Brow + 64, K, tid, rS, kbS);
  stage_half(B1 + 8192, Brow + 128L * K + 64, K, tid, rS, kbS);
  asm volatile("s_waitcnt vmcnt(0)" ::: "memory");   // order-independent drain
  __builtin_amdgcn_s_barrier();
  asm volatile("" ::: "memory");

  const int NI = K >> 7;        // 2 K-tiles (BK=64) per iteration
  const int tmask = 2 * NI - 1; // clamp for tail prefetches (never read)
#pragma unroll 1
  for (int i = 0; i < NI; ++i) {
    const int t1 = 2 * i + 1;
    const int t2 = (2 * i + 2) & tmask;
    const int t3 = (2 * i + 3) & tmask;
    // tile 2i from buf0; prefetch A(t1)->buf1 (ph1-2), B(t2)->buf0 (ph3-4)
    phase<0, true , false>(acc, bfr, A0, B0, rowA, rowB, kHi, Arow + (long)t1 * 64,            A1,        K, tid, rS, kbS);
    phase<1, false, false>(acc, bfr, A0, B0, rowA, rowB, kHi, Arow + 128L * K + (long)t1 * 64, A1 + 8192, K, tid, rS, kbS);
    phase<2, false, false>(acc, bfr, A0, B0, rowA, rowB, kHi, Brow + (long)t2 * 64,            B0,        K, tid, rS, kbS);
    phase<3, false, true >(acc, bfr, A0, B0, rowA, rowB, kHi, Brow + 128L * K + (long)t2 * 64, B0 + 8192, K, tid, rS, kbS);
    // tile 2i+1 from buf1; prefetch A(t2)->buf0 (ph5-6), B(t3)->buf1 (ph7-8)
    phase<0, true , false>(acc, bfr, A1, B1, rowA, rowB, kHi, Arow + (long)t2 * 64,            A0,        K, tid, rS, kbS);
    phase<1, false, false>(acc, bfr, A1, B1, rowA, rowB, kHi, Arow + 128L * K + (long)t2 * 64, A0 + 8192, K, tid, rS, kbS);
    phase<2, false, false>(acc, bfr, A1, B1, rowA, rowB, kHi, Brow + (long)t3 * 64,            B1,        K, tid, rS, kbS);
    phase<3, false, true >(acc, bfr, A1, B1, rowA, rowB, kHi, Brow + 128L * K + (long)t3 * 64, B1 + 8192, K, tid, rS, kbS);
  }
  // retire wrap-around tail prefetches before epilogue / endpgm
  asm volatile("s_waitcnt vmcnt(0)" ::: "memory");

  // epilogue: C/D layout col = lane&15, row = (lane>>4)*4 + reg (m89/m91)
  const long r0 = bm + wr * 128 + (lane >> 4) * 4;
  const long c0 = bn + wc * 64 + (lane & 15);
  if (EPI == 0) {
    ushort_t* C = (ushort_t*)Cout;
#pragma unroll
    for (int j = 0; j < 4; ++j) {
      const long col = c0 + j * 16;
      const float bv = bias[col];
#pragma unroll
      for (int i2 = 0; i2 < 8; ++i2)
#pragma unroll
        for (int r = 0; r < 4; ++r)
          C[(r0 + i2 * 16 + r) * N + col] = f2bf(acc[i2][j][r] + bv);
    }
  } else {
    float* C = (float*)Cout;
#pragma unroll
    for (int j = 0; j < 4; ++j) {
      const long col = c0 + j * 16;
#pragma unroll
      for (int i2 = 0; i2 < 8; ++i2)
#pragma unroll
        for (int r = 0; r < 4; ++r)
          C[(r0 + i2 * 16 + r) * N + col] = acc[i2][j][r];
    }
  }
}

// ---------------- LayerNorm + fast GELU, in-place on bf16 h ----------------
__global__ void __launch_bounds__(256) ln_gelu(ushort_t* __restrict__ h,
                                               const float* __restrict__ gamma,
                                               const float* __restrict__ beta) {
  const int D = 4096;
  ushort_t* p = h + (long)blockIdx.x * D + threadIdx.x * 16;
  uint4 u0 = *(const uint4*)p;
  uint4 u1 = *(const uint4*)(p + 8);
  unsigned w[8] = {u0.x, u0.y, u0.z, u0.w, u1.x, u1.y, u1.z, u1.w};
  float x[16];
#pragma unroll
  for (int k = 0; k < 8; ++k) {
    x[2 * k]     = __builtin_bit_cast(float, w[k] << 16);
    x[2 * k + 1] = __builtin_bit_cast(float, w[k] & 0xFFFF0000u);
  }
  float s = 0.f, q = 0.f;
#pragma unroll
  for (int k = 0; k < 16; ++k) { s += x[k]; q += x[k] * x[k]; }
#pragma unroll
  for (int m = 1; m < 64; m <<= 1) {
    s += __shfl_xor(s, m, 64);
    q += __shfl_xor(q, m, 64);
  }
  __shared__ float rs[4], rq[4];
  const int wid = threadIdx.x >> 6;
  if ((threadIdx.x & 63) == 0) { rs[wid] = s; rq[wid] = q; }
  __syncthreads();
  s = rs[0] + rs[1] + rs[2] + rs[3];
  q = rq[0] + rq[1] + rq[2] + rq[3];
  const float mu = s * (1.f / 4096.f);
  const float var = q * (1.f / 4096.f) - mu * mu;
  const float rstd = rsqrtf(var + 1e-5f);

  const int cb = threadIdx.x * 16;
  float gm[16], bt[16];
#pragma unroll
  for (int k = 0; k < 4; ++k) {
    *(float4*)&gm[k * 4] = *(const float4*)&gamma[cb + k * 4];
    *(float4*)&bt[k * 4] = *(const float4*)&beta[cb + k * 4];
  }
  unsigned o[8];
#pragma unroll
  for (int k = 0; k < 16; ++k) {
    float y = (x[k] - mu) * rstd * gm[k] + bt[k];
    float z = -1.5957691216f * __builtin_fmaf(0.044715f * y, y * y, y);
    float g = y * __builtin_amdgcn_rcpf(1.f + __expf(z));
    ushort_t b = f2bf(g);
    if (k & 1) o[k >> 1] |= ((unsigned)b) << 16; else o[k >> 1] = (unsigned)b;
  }
  uint4 v0, v1;
  v0.x = o[0]; v0.y = o[1]; v0.z = o[2]; v0.w = o[3];
  v1.x = o[4]; v1.y = o[5]; v1.z = o[6]; v1.w = o[7];
  *(uint4*)p = v0;
  *(uint4*)(p + 8) = v1;
}

extern "C" void kernel_launch(void* const* d_in, const int* in_sizes, int n_in,
                              void* d_out, int out_size, void* d_ws, size_t ws_size,
                              hipStream_t stream) {
  const float* emb   = (const float*)d_in[0];
  const float* W1    = (const float*)d_in[1];
  const float* b1    = (const float*)d_in[2];
  const float* gamma = (const float*)d_in[3];
  const float* beta  = (const float*)d_in[4];
  const float* W2    = (const float*)d_in[5];
  float* out = (float*)d_out;

  const int B = 16384, DIN = 1024, DH = 4096, DOUT = 1024;
  char* ws = (char*)d_ws;
  ushort_t* h    = (ushort_t*)(ws);                 // 134217728 B
  ushort_t* embB = (ushort_t*)(ws + 134217728);     //  33554432 B
  ushort_t* w1t  = (ushort_t*)(ws + 167772160);     //   8388608 B
  ushort_t* w2t  = (ushort_t*)(ws + 176160768);     //   8388608 B

  cast_kernel<<<4096, 256, 0, stream>>>(emb, embB, (long)B * DIN);
  transpose_cast<<<dim3(DH / 32, DIN / 32), dim3(32, 8), 0, stream>>>(W1, w1t, DIN, DH);
  transpose_cast<<<dim3(DOUT / 32, DH / 32), dim3(32, 8), 0, stream>>>(W2, w2t, DH, DOUT);
  gemm256<0><<<(B / 256) * (DH / 256), 512, 0, stream>>>(embB, w1t, b1, h, DH, DIN, DH / 256);
  ln_gelu<<<B, 256, 0, stream>>>(h, gamma, beta);
  gemm256<1><<<(B / 256) * (DOUT / 256), 512, 0, stream>>>(h, w2t, nullptr, out, DOUT, DH, DOUT / 256);
}